// Round 5
// baseline (177.863 us; speedup 1.0000x reference)
//
#include <hip/hip_runtime.h>

// B=128, V=300, MAX_VISITS=510, D=256, VOCAB=50000, MAX_DAYS=365.
#define MAXV 510
#define D4 64  // D/4 float4 per row

typedef float floatx4 __attribute__((ext_vector_type(4)));

// ---- Kernel 1: scatter slot->visit inverse map + per-visit segment offsets ----
// (inv is pre-initialized to -1 via hipMemsetAsync(0xFF))
__global__ __launch_bounds__(256) void build_maps(
    const int* __restrict__ c2v,
    const int* __restrict__ person,
    const int* __restrict__ slot,
    int* __restrict__ inv,     // [B*MAXV]
    int* __restrict__ off,     // [total_visits+1]
    int total_codes, int total_visits)
{
    int v = blockIdx.x * blockDim.x + threadIdx.x;
    if (v >= total_visits) return;
    inv[person[v] * MAXV + slot[v]] = v;
    int lo = 0, hi = total_codes;
    while (lo < hi) {
        int m = (lo + hi) >> 1;
        if (c2v[m] < v) lo = m + 1; else hi = m;
    }
    off[v] = lo;
    if (v == 0) off[total_visits] = total_codes;
}

// ---- Kernel 2: fused pad-fill + segment-sum + time embedding ----
// One wave per output slot; lane l owns dims [4l, 4l+4).
// All (up to) 16 row-gathers of a visit issue back-to-back before any wait:
// one memory round-trip per visit instead of three (round-4 theory: the
// kernel is latency x outstanding bound, not bandwidth bound).
__global__ __launch_bounds__(256) void fused_kernel(
    const int* __restrict__ all_codes,
    const float* __restrict__ times,
    const floatx4* __restrict__ emb,  // [VOCAB, D4]
    const floatx4* __restrict__ pad,  // [D4]
    const floatx4* __restrict__ tsc,  // [32] = 128 timescales
    const int* __restrict__ inv,      // [nslots]
    const int* __restrict__ off,      // [total_visits+1]
    floatx4* __restrict__ out,        // [nslots, D4]
    int nslots)
{
    const int tid = threadIdx.x;
    const int w = tid >> 6;
    const int lane = tid & 63;
    const int slot_id = blockIdx.x * 4 + w;
    if (slot_id >= nslots) return;

    const int v = inv[slot_id];
    if (v < 0) {
        __builtin_nontemporal_store(pad[lane], &out[slot_id * D4 + lane]);
        return;
    }

    const int lo = off[v];
    const int hi = off[v + 1];
    const int cnt = hi - lo;

    // Hoist time-embedding compute so it overlaps the gather round-trip.
    float t = times[v];
    t = fminf(fmaxf(t, 0.f), 364.f);
    const floatx4 ts = tsc[lane & 31];
    floatx4 te;
    if (lane < 32) {
        te.x = sinf(t * ts.x); te.y = sinf(t * ts.y);
        te.z = sinf(t * ts.z); te.w = sinf(t * ts.w);
    } else {
        te.x = cosf(t * ts.x); te.y = cosf(t * ts.y);
        te.z = cosf(t * ts.z); te.w = cosf(t * ts.w);
    }

    floatx4 acc = te;
    for (int base = 0; base < cnt; base += 16) {
        const int rem = cnt - base;            // >= 1
        const int rmax = rem - 1;
        // One coalesced lane-load of up to 16 codes (clamped).
        const int mycode = all_codes[lo + base + min(lane, rmax)];

        int c[16];
#pragma unroll
        for (int j = 0; j < 16; ++j)
            c[j] = __shfl(mycode, min(j, rmax));   // wave-uniform broadcast

        floatx4 e[16];
#pragma unroll
        for (int j = 0; j < 16; ++j)               // 16 loads in flight
            e[j] = emb[(size_t)c[j] * D4 + lane];

#pragma unroll
        for (int j = 0; j < 16; ++j) {             // masked accumulate
            if (j < rem) acc += e[j];
        }
    }

    __builtin_nontemporal_store(acc, &out[slot_id * D4 + lane]);
}

extern "C" void kernel_launch(void* const* d_in, const int* in_sizes, int n_in,
                              void* d_out, int out_size, void* d_ws, size_t ws_size,
                              hipStream_t stream) {
    const int*   all_codes = (const int*)d_in[0];
    const int*   c2v       = (const int*)d_in[1];
    const int*   person    = (const int*)d_in[2];
    const int*   slot      = (const int*)d_in[3];
    const float* times     = (const float*)d_in[4];
    const float* emb       = (const float*)d_in[5];
    const float* pad       = (const float*)d_in[6];
    const float* tsc       = (const float*)d_in[7];

    const int total_codes  = in_sizes[0];
    const int total_visits = in_sizes[2];
    const int nslots       = out_size / 256;   // B * MAXV

    int* inv = (int*)d_ws;                     // [nslots]
    int* off = inv + nslots;                   // [total_visits+1]

    (void)hipMemsetAsync(inv, 0xFF, (size_t)nslots * sizeof(int), stream);

    build_maps<<<(total_visits + 255) / 256, 256, 0, stream>>>(
        c2v, person, slot, inv, off, total_codes, total_visits);

    fused_kernel<<<(nslots + 3) / 4, 256, 0, stream>>>(
        all_codes, times, (const floatx4*)emb, (const floatx4*)pad,
        (const floatx4*)tsc, inv, off, (floatx4*)d_out, nslots);
}

// Round 6
// 165.597 us; speedup vs baseline: 1.0741x; 1.0741x over previous
//
#include <hip/hip_runtime.h>

// B=128, V=300, MAX_VISITS=510, D=256, VOCAB=50000, MAX_DAYS=365.
#define MAXV 510
#define D4 64  // D/4 float4 per row

typedef float floatx4 __attribute__((ext_vector_type(4)));

__device__ __forceinline__ unsigned int pack2_bf16_rne(float a, float b) {
    unsigned int ua = __builtin_bit_cast(unsigned int, a);
    unsigned int ub = __builtin_bit_cast(unsigned int, b);
    ua = (ua + 0x7FFFu + ((ua >> 16) & 1u)) >> 16;
    ub = (ub + 0x7FFFu + ((ub >> 16) & 1u)) >> 16;
    return ua | (ub << 16);
}

__device__ __forceinline__ float bf16_to_f32(unsigned short u) {
    return __builtin_bit_cast(float, (unsigned int)u << 16);
}

// ---- Kernel 0: fp32 -> bf16 table conversion (d_ws is re-poisoned each call,
// so this must run every launch). Thread: 2x float4 in -> 1x uint4 out (16B).
__global__ __launch_bounds__(256) void convert_bf16(
    const float4* __restrict__ in, uint4* __restrict__ out, int npairs) {
    int i = blockIdx.x * blockDim.x + threadIdx.x;
    if (i >= npairs) return;
    const float4 a = in[2 * i];
    const float4 b = in[2 * i + 1];
    uint4 r;
    r.x = pack2_bf16_rne(a.x, a.y);
    r.y = pack2_bf16_rne(a.z, a.w);
    r.z = pack2_bf16_rne(b.x, b.y);
    r.w = pack2_bf16_rne(b.z, b.w);
    out[i] = r;
}

// ---- Kernel 1: scatter slot->visit inverse map + per-visit segment offsets ----
__global__ __launch_bounds__(256) void build_maps(
    const int* __restrict__ c2v,
    const int* __restrict__ person,
    const int* __restrict__ slot,
    int* __restrict__ inv,     // [B*MAXV]
    int* __restrict__ off,     // [total_visits+1]
    int total_codes, int total_visits)
{
    int v = blockIdx.x * blockDim.x + threadIdx.x;
    if (v >= total_visits) return;
    inv[person[v] * MAXV + slot[v]] = v;
    int lo = 0, hi = total_codes;
    while (lo < hi) {
        int m = (lo + hi) >> 1;
        if (c2v[m] < v) lo = m + 1; else hi = m;
    }
    off[v] = lo;
    if (v == 0) off[total_visits] = total_codes;
}

// ---- Kernel 2 (bf16 path): fused pad-fill + segment-sum + time embedding ----
// One wave per slot; lane l owns dims [4l,4l+4): 8B bf16x4 row reads (512B/row).
__global__ __launch_bounds__(256) void fused_bf16(
    const int* __restrict__ all_codes,
    const float* __restrict__ times,
    const ushort4* __restrict__ embh, // [VOCAB, 64] bf16x4
    const floatx4* __restrict__ pad,  // [D4]
    const floatx4* __restrict__ tsc,  // [32]
    const int* __restrict__ inv,
    const int* __restrict__ off,
    floatx4* __restrict__ out,
    int nslots)
{
    const int tid = threadIdx.x;
    const int w = tid >> 6;
    const int lane = tid & 63;
    const int slot_id = blockIdx.x * 4 + w;
    if (slot_id >= nslots) return;

    const int v = inv[slot_id];
    if (v < 0) {
        __builtin_nontemporal_store(pad[lane], &out[slot_id * D4 + lane]);
        return;
    }

    const int lo = off[v];
    const int hi = off[v + 1];
    const int cnt = hi - lo;

    float t = times[v];
    t = fminf(fmaxf(t, 0.f), 364.f);
    const floatx4 ts = tsc[lane & 31];
    floatx4 acc;
    if (lane < 32) {
        acc.x = sinf(t * ts.x); acc.y = sinf(t * ts.y);
        acc.z = sinf(t * ts.z); acc.w = sinf(t * ts.w);
    } else {
        acc.x = cosf(t * ts.x); acc.y = cosf(t * ts.y);
        acc.z = cosf(t * ts.z); acc.w = cosf(t * ts.w);
    }

    for (int base = 0; base < cnt; base += 64) {
        const int n = min(cnt - base, 64);
        const int mycode = all_codes[lo + base + min(lane, n - 1)];
        for (int j = 0; j < n; j += 4) {
            const int i1 = min(j + 1, n - 1);
            const int i2 = min(j + 2, n - 1);
            const int i3 = min(j + 3, n - 1);
            const int c0 = __shfl(mycode, j);
            const int c1 = __shfl(mycode, i1);
            const int c2 = __shfl(mycode, i2);
            const int c3 = __shfl(mycode, i3);
            const ushort4 e0 = embh[c0 * D4 + lane];
            const ushort4 e1 = embh[c1 * D4 + lane];
            const ushort4 e2 = embh[c2 * D4 + lane];
            const ushort4 e3 = embh[c3 * D4 + lane];
            acc.x += bf16_to_f32(e0.x); acc.y += bf16_to_f32(e0.y);
            acc.z += bf16_to_f32(e0.z); acc.w += bf16_to_f32(e0.w);
            if (j + 1 < n) { acc.x += bf16_to_f32(e1.x); acc.y += bf16_to_f32(e1.y);
                             acc.z += bf16_to_f32(e1.z); acc.w += bf16_to_f32(e1.w); }
            if (j + 2 < n) { acc.x += bf16_to_f32(e2.x); acc.y += bf16_to_f32(e2.y);
                             acc.z += bf16_to_f32(e2.z); acc.w += bf16_to_f32(e2.w); }
            if (j + 3 < n) { acc.x += bf16_to_f32(e3.x); acc.y += bf16_to_f32(e3.y);
                             acc.z += bf16_to_f32(e3.z); acc.w += bf16_to_f32(e3.w); }
        }
    }

    __builtin_nontemporal_store(acc, &out[slot_id * D4 + lane]);
}

// ---- Kernel 2 (fp32 fallback, if ws too small for the bf16 table) ----
__global__ __launch_bounds__(256) void fused_f32(
    const int* __restrict__ all_codes,
    const float* __restrict__ times,
    const floatx4* __restrict__ emb,
    const floatx4* __restrict__ pad,
    const floatx4* __restrict__ tsc,
    const int* __restrict__ inv,
    const int* __restrict__ off,
    floatx4* __restrict__ out,
    int nslots)
{
    const int tid = threadIdx.x;
    const int w = tid >> 6;
    const int lane = tid & 63;
    const int slot_id = blockIdx.x * 4 + w;
    if (slot_id >= nslots) return;

    const int v = inv[slot_id];
    if (v < 0) {
        __builtin_nontemporal_store(pad[lane], &out[slot_id * D4 + lane]);
        return;
    }
    const int lo = off[v];
    const int hi = off[v + 1];
    const int cnt = hi - lo;

    float t = times[v];
    t = fminf(fmaxf(t, 0.f), 364.f);
    const floatx4 ts = tsc[lane & 31];
    floatx4 acc;
    if (lane < 32) {
        acc.x = sinf(t * ts.x); acc.y = sinf(t * ts.y);
        acc.z = sinf(t * ts.z); acc.w = sinf(t * ts.w);
    } else {
        acc.x = cosf(t * ts.x); acc.y = cosf(t * ts.y);
        acc.z = cosf(t * ts.z); acc.w = cosf(t * ts.w);
    }
    for (int i = lo; i < hi; ++i) {
        const int c = all_codes[i];
        acc += emb[(size_t)c * D4 + lane];
    }
    __builtin_nontemporal_store(acc, &out[slot_id * D4 + lane]);
}

extern "C" void kernel_launch(void* const* d_in, const int* in_sizes, int n_in,
                              void* d_out, int out_size, void* d_ws, size_t ws_size,
                              hipStream_t stream) {
    const int*   all_codes = (const int*)d_in[0];
    const int*   c2v       = (const int*)d_in[1];
    const int*   person    = (const int*)d_in[2];
    const int*   slot      = (const int*)d_in[3];
    const float* times     = (const float*)d_in[4];
    const float* emb       = (const float*)d_in[5];
    const float* pad       = (const float*)d_in[6];
    const float* tsc       = (const float*)d_in[7];

    const int total_codes  = in_sizes[0];
    const int total_visits = in_sizes[2];
    const int emb_elems    = in_sizes[5];      // VOCAB * D
    const int nslots       = out_size / 256;   // B * MAXV

    char* ws = (char*)d_ws;
    int* inv = (int*)ws;                       // [nslots]
    int* off = inv + nslots;                   // [total_visits+1]
    size_t head = ((size_t)(nslots + total_visits + 1) * sizeof(int) + 255) & ~(size_t)255;
    unsigned short* embh = (unsigned short*)(ws + head);
    const size_t needed = head + (size_t)emb_elems * sizeof(unsigned short);

    (void)hipMemsetAsync(inv, 0xFF, (size_t)nslots * sizeof(int), stream);

    build_maps<<<(total_visits + 255) / 256, 256, 0, stream>>>(
        c2v, person, slot, inv, off, total_codes, total_visits);

    if (ws_size >= needed) {
        const int npairs = emb_elems / 8;      // two float4 per thread
        convert_bf16<<<(npairs + 255) / 256, 256, 0, stream>>>(
            (const float4*)emb, (uint4*)embh, npairs);
        fused_bf16<<<(nslots + 3) / 4, 256, 0, stream>>>(
            all_codes, times, (const ushort4*)embh, (const floatx4*)pad,
            (const floatx4*)tsc, inv, off, (floatx4*)d_out, nslots);
    } else {
        fused_f32<<<(nslots + 3) / 4, 256, 0, stream>>>(
            all_codes, times, (const floatx4*)emb, (const floatx4*)pad,
            (const floatx4*)tsc, inv, off, (floatx4*)d_out, nslots);
    }
}